// Round 5
// baseline (96.063 us; speedup 1.0000x reference)
//
#include <hip/hip_runtime.h>
#include <math.h>

#define IM 64
#define NBATCH 256
#define HID 64

typedef _Float16 f16;
typedef _Float16 f16x8 __attribute__((ext_vector_type(8)));
typedef _Float16 f16x4 __attribute__((ext_vector_type(4)));
typedef _Float16 f16x2 __attribute__((ext_vector_type(2)));
typedef float    f32x4 __attribute__((ext_vector_type(4)));

// wt[m][p][n][k] = (f16) w_m[p][k][n]  (m=0 -> w1, m=1 -> w2); n=out-chan, k=in-chan
__global__ void prep_kernel(const float* __restrict__ w1,
                            const float* __restrict__ w2,
                            f16* __restrict__ wt) {
    int idx = blockIdx.x * 256 + threadIdx.x;   // 0 .. 16383
    int m  = idx >> 13;
    int r  = idx & 8191;
    int p  = r >> 12;
    int nk = r & 4095;
    int n  = nk >> 6, k = nk & 63;
    const float* w = m ? w2 : w1;
    wt[idx] = (f16)w[p*4096 + k*64 + n];
}

static __device__ __forceinline__ f16x2 cvt2(float a, float b) {
    return __builtin_bit_cast(f16x2, __builtin_amdgcn_cvt_pkrtz(a, b));
}

// 256-thread blocks = 4 independent waves (4 consecutive image rows of one
// image). Each wave owns a private 8 KB LDS tile; NO barriers anywhere.
// tile[pixel][chan] f16, XOR swizzle elem = p*64 + (c ^ ((p&7)<<3)).
__global__ __launch_bounds__(256, 4) void genmodel_kernel(
    const int*   __restrict__ program_id,
    const int*   __restrict__ shape_ids,
    const float* __restrict__ raw_positions,
    const float* __restrict__ g_w0, const float* __restrict__ g_b0,
    const float* __restrict__ g_b1, const float* __restrict__ g_b2,
    const float* __restrict__ g_w3, const float* __restrict__ g_b3,
    const float* __restrict__ g_lmr,
    const f16*   __restrict__ wt,
    float* __restrict__ out)
{
    __shared__ f16 tile[4][HID*HID];         // 8 KB per wave, wave-private

    const int tid  = threadIdx.x;
    const int wave = tid >> 6;
    const int lane = tid & 63;
    const int u = lane & 15, g = lane >> 4;
    f16* tb = &tile[wave][0];

    const int gw   = blockIdx.x * 4 + wave;  // global wave id = image-row id
    const int b    = gw >> 6;
    const int irow = gw & 63;

    const float cx = -1.0f + (2.0f/63.0f)*(float)lane;
    const float cy = -1.0f + (2.0f/63.0f)*(float)irow;

    const int pid = __builtin_amdgcn_readfirstlane(program_id[b]);
    const int ns  = (pid == 0) ? 1 : 2;

    float p0 = 0.f, p1 = 0.f;

    #pragma unroll 1
    for (int s = 0; s < ns; ++s) {
        const int pg = __builtin_amdgcn_readfirstlane(shape_ids[b*2 + s]);
        const float rx = raw_positions[(b*2+s)*2 + 0];
        const float ry = raw_positions[(b*2+s)*2 + 1];
        const float posx = 1.f/(1.f + expf(-rx)) - 0.5f;
        const float posy = 1.f/(1.f + expf(-ry)) - 0.5f;
        const float dx = cx - posx, dy = cy - posy;
        const float theta = atan2f(dy, dx);

        // thetas of the 4 pixel-columns this lane covers in B-fragments
        float th[4];
        #pragma unroll
        for (int nt = 0; nt < 4; ++nt) th[nt] = __shfl(theta, 16*nt + u);

        // ---- layer 0 (1->64): straight into MFMA B-fragment registers
        f16x8 bf[4][2];
        {
            const float* w0p = g_w0 + pg*HID;
            const float* b0p = g_b0 + pg*HID;
            f32x4 w0r[2][2], b0r[2][2];
            #pragma unroll
            for (int kh = 0; kh < 2; ++kh)
                #pragma unroll
                for (int q = 0; q < 2; ++q) {
                    w0r[kh][q] = *(const f32x4*)(w0p + 32*kh + 8*g + 4*q);
                    b0r[kh][q] = *(const f32x4*)(b0p + 32*kh + 8*g + 4*q);
                }
            #pragma unroll
            for (int nt = 0; nt < 4; ++nt)
                #pragma unroll
                for (int kh = 0; kh < 2; ++kh) {
                    union { f16x2 h2[4]; f16x8 v8; } uu;
                    #pragma unroll
                    for (int q = 0; q < 2; ++q)
                        #pragma unroll
                        for (int j = 0; j < 4; j += 2) {
                            float a = fmaxf(fmaf(th[nt], w0r[kh][q][j],   b0r[kh][q][j]),   0.f);
                            float c = fmaxf(fmaf(th[nt], w0r[kh][q][j+1], b0r[kh][q][j+1]), 0.f);
                            uu.h2[q*2 + j/2] = cvt2(a, c);
                        }
                    bf[nt][kh] = uu.v8;
                }
        }

        // ---- layer 1: D[out-chan][pixel] = W1-frag (A) x act (B), to LDS
        {
            const f16* W1 = wt + pg*4096;
            #pragma unroll
            for (int mt = 0; mt < 4; ++mt) {
                const f16x8 wf0 = *(const f16x8*)&W1[(16*mt+u)*64 +      8*g];
                const f16x8 wf1 = *(const f16x8*)&W1[(16*mt+u)*64 + 32 + 8*g];
                const f32x4 bv  = *(const f32x4*)(g_b1 + pg*HID + 16*mt + 4*g);
                #pragma unroll
                for (int nt = 0; nt < 4; ++nt) {
                    f32x4 acc = bv;
                    acc = __builtin_amdgcn_mfma_f32_16x16x32_f16(wf0, bf[nt][0], acc, 0,0,0);
                    acc = __builtin_amdgcn_mfma_f32_16x16x32_f16(wf1, bf[nt][1], acc, 0,0,0);
                    union { f16x2 h2[2]; f16x4 v4; } r;
                    r.h2[0] = cvt2(fmaxf(acc[0],0.f), fmaxf(acc[1],0.f));
                    r.h2[1] = cvt2(fmaxf(acc[2],0.f), fmaxf(acc[3],0.f));
                    const int p_ = 16*nt + u;
                    *(f16x4*)&tb[p_*64 + ((16*mt + 4*g) ^ ((u&7)<<3))] = r.v4;
                }
            }
        }

        // ---- layer 2 + head fused
        {
            f16x8 cf[4][2];
            #pragma unroll
            for (int nt = 0; nt < 4; ++nt)
                #pragma unroll
                for (int kh = 0; kh < 2; ++kh) {
                    const int p_ = 16*nt + u;
                    cf[nt][kh] = *(const f16x8*)&tb[p_*64 + ((32*kh + 8*g) ^ ((u&7)<<3))];
                }
            const f16* W2 = wt + 8192 + pg*4096;
            float hp[4] = {0.f, 0.f, 0.f, 0.f};
            #pragma unroll
            for (int mt = 0; mt < 4; ++mt) {
                const f16x8 wf0 = *(const f16x8*)&W2[(16*mt+u)*64 +      8*g];
                const f16x8 wf1 = *(const f16x8*)&W2[(16*mt+u)*64 + 32 + 8*g];
                const f32x4 bv  = *(const f32x4*)(g_b2 + pg*HID + 16*mt + 4*g);
                const f32x4 w3v = *(const f32x4*)(g_w3 + pg*HID + 16*mt + 4*g);
                #pragma unroll
                for (int nt = 0; nt < 4; ++nt) {
                    f32x4 acc = bv;
                    acc = __builtin_amdgcn_mfma_f32_16x16x32_f16(wf0, cf[nt][0], acc, 0,0,0);
                    acc = __builtin_amdgcn_mfma_f32_16x16x32_f16(wf1, cf[nt][1], acc, 0,0,0);
                    hp[nt] += fmaxf(acc[0],0.f)*w3v[0] + fmaxf(acc[1],0.f)*w3v[1]
                            + fmaxf(acc[2],0.f)*w3v[2] + fmaxf(acc[3],0.f)*w3v[3];
                }
            }
            #pragma unroll
            for (int nt = 0; nt < 4; ++nt) {
                hp[nt] += __shfl_xor(hp[nt], 16);
                hp[nt] += __shfl_xor(hp[nt], 32);
            }
            float ov = hp[0];
            if (g == 1) ov = hp[1];
            if (g == 2) ov = hp[2];
            if (g == 3) ov = hp[3];
            ov += g_b3[pg];

            const float mult  = expf(g_lmr[pg]);
            const float r2    = sqrtf(dx*dx + dy*dy);
            const float logit = mult * (expf(ov) - r2);
            const float p     = 1.f/(1.f + expf(-logit));
            if (s == 0) p0 = p; else p1 = p;
        }
    }

    float res;
    if (pid == 0) {
        res = p0;
    } else {
        float c = (pid == 2) ? (p0 - p1) : (p0 + p1);
        res = fminf(fmaxf(c, 0.f), 1.f);
    }
    out[b*(IM*IM) + irow*64 + lane] = res;
}

extern "C" void kernel_launch(void* const* d_in, const int* in_sizes, int n_in,
                              void* d_out, int out_size, void* d_ws, size_t ws_size,
                              hipStream_t stream) {
    const int*   program_id    = (const int*)  d_in[0];
    const int*   shape_ids     = (const int*)  d_in[1];
    const float* raw_positions = (const float*)d_in[2];
    const float* w0            = (const float*)d_in[3];
    const float* b0            = (const float*)d_in[4];
    const float* w1            = (const float*)d_in[5];
    const float* b1            = (const float*)d_in[6];
    const float* w2            = (const float*)d_in[7];
    const float* b2            = (const float*)d_in[8];
    const float* w3            = (const float*)d_in[9];
    const float* b3            = (const float*)d_in[10];
    const float* lmr           = (const float*)d_in[11];
    float* out = (float*)d_out;
    f16*   wt  = (f16*)d_ws;                 // 16384 f16 = 32 KB

    prep_kernel<<<64, 256, 0, stream>>>(w1, w2, wt);

    genmodel_kernel<<<NBATCH*16, 256, 0, stream>>>(
        program_id, shape_ids, raw_positions,
        w0, b0, b1, b2, w3, b3, lmr, wt, out);
}

// Round 6
// 83.021 us; speedup vs baseline: 1.1571x; 1.1571x over previous
//
#include <hip/hip_runtime.h>
#include <math.h>

#define IM 64
#define NBATCH 256
#define HID 64

typedef _Float16 f16;
typedef _Float16 f16x8 __attribute__((ext_vector_type(8)));
typedef _Float16 f16x4 __attribute__((ext_vector_type(4)));
typedef _Float16 f16x2 __attribute__((ext_vector_type(2)));
typedef float    f32x4 __attribute__((ext_vector_type(4)));

// wt[m][p][n][k] = (f16) w_m[p][k][n]  (m=0 -> w1, m=1 -> w2); n=out-chan, k=in-chan
__global__ void prep_kernel(const float* __restrict__ w1,
                            const float* __restrict__ w2,
                            f16* __restrict__ wt) {
    int idx = blockIdx.x * 256 + threadIdx.x;   // 0 .. 16383
    int m  = idx >> 13;
    int r  = idx & 8191;
    int p  = r >> 12;
    int nk = r & 4095;
    int n  = nk >> 6, k = nk & 63;
    const float* w = m ? w2 : w1;
    wt[idx] = (f16)w[p*4096 + k*64 + n];
}

static __device__ __forceinline__ f16x2 cvt2(float a, float b) {
    return __builtin_bit_cast(f16x2, __builtin_amdgcn_cvt_pkrtz(a, b));
}

// 128-thread blocks = 2 independent waves (2 consecutive image rows of one
// image). Each wave owns a private 8 KB LDS tile; NO barriers anywhere.
// tile[pixel][chan] f16, XOR swizzle elem = p*64 + (c ^ ((p&7)<<3)).
// launch_bounds(128,2): VGPR cap 256 -> NO spilling (R5 lesson: (256,4)
// forced a 64-VGPR tier and 38 MB of scratch traffic).
__global__ __launch_bounds__(128, 2) void genmodel_kernel(
    const int*   __restrict__ program_id,
    const int*   __restrict__ shape_ids,
    const float* __restrict__ raw_positions,
    const float* __restrict__ g_w0, const float* __restrict__ g_b0,
    const float* __restrict__ g_b1, const float* __restrict__ g_b2,
    const float* __restrict__ g_w3, const float* __restrict__ g_b3,
    const float* __restrict__ g_lmr,
    const f16*   __restrict__ wt,
    float* __restrict__ out)
{
    __shared__ f16 tile[2][HID*HID];         // 8 KB per wave, wave-private

    const int tid  = threadIdx.x;
    const int wave = tid >> 6;
    const int lane = tid & 63;
    const int u = lane & 15, g = lane >> 4;
    f16* tb = &tile[wave][0];

    const int gw   = blockIdx.x * 2 + wave;  // global wave id = image-row id
    const int b    = gw >> 6;
    const int irow = gw & 63;

    const float cx = -1.0f + (2.0f/63.0f)*(float)lane;
    const float cy = -1.0f + (2.0f/63.0f)*(float)irow;

    const int pid = __builtin_amdgcn_readfirstlane(program_id[b]);
    const int ns  = (pid == 0) ? 1 : 2;

    float p0 = 0.f, p1 = 0.f;

    #pragma unroll 1
    for (int s = 0; s < ns; ++s) {
        const int pg = __builtin_amdgcn_readfirstlane(shape_ids[b*2 + s]);
        const float rx = raw_positions[(b*2+s)*2 + 0];
        const float ry = raw_positions[(b*2+s)*2 + 1];
        const float posx = 1.f/(1.f + expf(-rx)) - 0.5f;
        const float posy = 1.f/(1.f + expf(-ry)) - 0.5f;
        const float dx = cx - posx, dy = cy - posy;
        const float theta = atan2f(dy, dx);

        // thetas of the 4 pixel-columns this lane covers in B-fragments
        float th[4];
        #pragma unroll
        for (int nt = 0; nt < 4; ++nt) th[nt] = __shfl(theta, 16*nt + u);

        // ---- layer 0 (1->64): straight into MFMA B-fragment registers
        f16x8 bf[4][2];
        {
            const float* w0p = g_w0 + pg*HID;
            const float* b0p = g_b0 + pg*HID;
            f32x4 w0r[2][2], b0r[2][2];
            #pragma unroll
            for (int kh = 0; kh < 2; ++kh)
                #pragma unroll
                for (int q = 0; q < 2; ++q) {
                    w0r[kh][q] = *(const f32x4*)(w0p + 32*kh + 8*g + 4*q);
                    b0r[kh][q] = *(const f32x4*)(b0p + 32*kh + 8*g + 4*q);
                }
            #pragma unroll
            for (int nt = 0; nt < 4; ++nt)
                #pragma unroll
                for (int kh = 0; kh < 2; ++kh) {
                    union { f16x2 h2[4]; f16x8 v8; } uu;
                    #pragma unroll
                    for (int q = 0; q < 2; ++q)
                        #pragma unroll
                        for (int j = 0; j < 4; j += 2) {
                            float a = fmaxf(fmaf(th[nt], w0r[kh][q][j],   b0r[kh][q][j]),   0.f);
                            float c = fmaxf(fmaf(th[nt], w0r[kh][q][j+1], b0r[kh][q][j+1]), 0.f);
                            uu.h2[q*2 + j/2] = cvt2(a, c);
                        }
                    bf[nt][kh] = uu.v8;
                }
        }

        // ---- layer 1: D[out-chan][pixel] = W1-frag (A) x act (B), to LDS
        {
            const f16* W1 = wt + pg*4096;
            #pragma unroll
            for (int mt = 0; mt < 4; ++mt) {
                const f16x8 wf0 = *(const f16x8*)&W1[(16*mt+u)*64 +      8*g];
                const f16x8 wf1 = *(const f16x8*)&W1[(16*mt+u)*64 + 32 + 8*g];
                const f32x4 bv  = *(const f32x4*)(g_b1 + pg*HID + 16*mt + 4*g);
                #pragma unroll
                for (int nt = 0; nt < 4; ++nt) {
                    f32x4 acc = bv;
                    acc = __builtin_amdgcn_mfma_f32_16x16x32_f16(wf0, bf[nt][0], acc, 0,0,0);
                    acc = __builtin_amdgcn_mfma_f32_16x16x32_f16(wf1, bf[nt][1], acc, 0,0,0);
                    union { f16x2 h2[2]; f16x4 v4; } r;
                    r.h2[0] = cvt2(fmaxf(acc[0],0.f), fmaxf(acc[1],0.f));
                    r.h2[1] = cvt2(fmaxf(acc[2],0.f), fmaxf(acc[3],0.f));
                    const int p_ = 16*nt + u;
                    *(f16x4*)&tb[p_*64 + ((16*mt + 4*g) ^ ((u&7)<<3))] = r.v4;
                }
            }
        }

        // ---- layer 2 + head fused
        {
            f16x8 cf[4][2];
            #pragma unroll
            for (int nt = 0; nt < 4; ++nt)
                #pragma unroll
                for (int kh = 0; kh < 2; ++kh) {
                    const int p_ = 16*nt + u;
                    cf[nt][kh] = *(const f16x8*)&tb[p_*64 + ((32*kh + 8*g) ^ ((u&7)<<3))];
                }
            const f16* W2 = wt + 8192 + pg*4096;
            float hp[4] = {0.f, 0.f, 0.f, 0.f};
            #pragma unroll
            for (int mt = 0; mt < 4; ++mt) {
                const f16x8 wf0 = *(const f16x8*)&W2[(16*mt+u)*64 +      8*g];
                const f16x8 wf1 = *(const f16x8*)&W2[(16*mt+u)*64 + 32 + 8*g];
                const f32x4 bv  = *(const f32x4*)(g_b2 + pg*HID + 16*mt + 4*g);
                const f32x4 w3v = *(const f32x4*)(g_w3 + pg*HID + 16*mt + 4*g);
                #pragma unroll
                for (int nt = 0; nt < 4; ++nt) {
                    f32x4 acc = bv;
                    acc = __builtin_amdgcn_mfma_f32_16x16x32_f16(wf0, cf[nt][0], acc, 0,0,0);
                    acc = __builtin_amdgcn_mfma_f32_16x16x32_f16(wf1, cf[nt][1], acc, 0,0,0);
                    hp[nt] += fmaxf(acc[0],0.f)*w3v[0] + fmaxf(acc[1],0.f)*w3v[1]
                            + fmaxf(acc[2],0.f)*w3v[2] + fmaxf(acc[3],0.f)*w3v[3];
                }
            }
            #pragma unroll
            for (int nt = 0; nt < 4; ++nt) {
                hp[nt] += __shfl_xor(hp[nt], 16);
                hp[nt] += __shfl_xor(hp[nt], 32);
            }
            float ov = hp[0];
            if (g == 1) ov = hp[1];
            if (g == 2) ov = hp[2];
            if (g == 3) ov = hp[3];
            ov += g_b3[pg];

            const float mult  = expf(g_lmr[pg]);
            const float r2    = sqrtf(dx*dx + dy*dy);
            const float logit = mult * (expf(ov) - r2);
            const float p     = 1.f/(1.f + expf(-logit));
            if (s == 0) p0 = p; else p1 = p;
        }
    }

    float res;
    if (pid == 0) {
        res = p0;
    } else {
        float c = (pid == 2) ? (p0 - p1) : (p0 + p1);
        res = fminf(fmaxf(c, 0.f), 1.f);
    }
    out[b*(IM*IM) + irow*64 + lane] = res;
}

extern "C" void kernel_launch(void* const* d_in, const int* in_sizes, int n_in,
                              void* d_out, int out_size, void* d_ws, size_t ws_size,
                              hipStream_t stream) {
    const int*   program_id    = (const int*)  d_in[0];
    const int*   shape_ids     = (const int*)  d_in[1];
    const float* raw_positions = (const float*)d_in[2];
    const float* w0            = (const float*)d_in[3];
    const float* b0            = (const float*)d_in[4];
    const float* w1            = (const float*)d_in[5];
    const float* b1            = (const float*)d_in[6];
    const float* w2            = (const float*)d_in[7];
    const float* b2            = (const float*)d_in[8];
    const float* w3            = (const float*)d_in[9];
    const float* b3            = (const float*)d_in[10];
    const float* lmr           = (const float*)d_in[11];
    float* out = (float*)d_out;
    f16*   wt  = (f16*)d_ws;                 // 16384 f16 = 32 KB

    prep_kernel<<<64, 256, 0, stream>>>(w1, w2, wt);

    genmodel_kernel<<<NBATCH*32, 128, 0, stream>>>(
        program_id, shape_ids, raw_positions,
        w0, b0, b1, b2, w3, b3, lmr, wt, out);
}

// Round 7
// 82.115 us; speedup vs baseline: 1.1699x; 1.0110x over previous
//
#include <hip/hip_runtime.h>
#include <math.h>

#define IM 64
#define NBATCH 256
#define HID 64

typedef _Float16 f16;
typedef _Float16 f16x8 __attribute__((ext_vector_type(8)));
typedef _Float16 f16x2 __attribute__((ext_vector_type(2)));
typedef float    f32x4 __attribute__((ext_vector_type(4)));

// Packed A-fragment weight layouts, 8 f16 per lane, fully coalesced:
//   wt1[(((pg*4+mt)*2+kh)*64 + lane)*8 + j] = W1[k][n=16mt+u],  k = 32kh+8g+j        (std k-order)
//   wt2[(((pg*4+mt)*2+kh)*64 + lane)*8 + j] = W2[k][n=16mt+u],  k = 32kh+16(j>>2)+4g+(j&3)
// wt2's k-permutation matches the natural in-register layout of layer-1's
// MFMA accumulators, so layer 2 needs NO LDS / NO shuffles (MFMA = slot-wise
// dot: any fixed k-permutation applied to BOTH operands is legal).
__global__ void prep_kernel(const float* __restrict__ w1,
                            const float* __restrict__ w2,
                            f16* __restrict__ wt) {
    int idx  = blockIdx.x * 256 + threadIdx.x;   // 0..16383
    int half = idx >> 13;                        // 0: wt1, 1: wt2
    int r    = idx & 8191;
    int j    = r & 7;
    int lane = (r >> 3) & 63;
    int kh   = (r >> 9) & 1;
    int mt   = (r >> 10) & 3;
    int pg   = (r >> 12) & 1;
    int u = lane & 15, g = lane >> 4;
    int n = 16*mt + u;
    int k;
    float v;
    if (half == 0) { k = 32*kh + 8*g + j;                 v = w1[pg*4096 + k*64 + n]; }
    else           { k = 32*kh + 16*(j>>2) + 4*g + (j&3); v = w2[pg*4096 + k*64 + n]; }
    wt[idx] = (f16)v;
}

static __device__ __forceinline__ f16x2 cvt2(float a, float b) {
    return __builtin_bit_cast(f16x2, __builtin_amdgcn_cvt_pkrtz(a, b));
}

// 256-thread blocks = 4 independent waves (4 image rows of one image).
// NO LDS, NO barriers: occupancy bounded by VGPR only.
// launch_bounds(256,2): VGPR cap 256 -> no spill (R5 lesson).
__global__ __launch_bounds__(256, 2) void genmodel_kernel(
    const int*   __restrict__ program_id,
    const int*   __restrict__ shape_ids,
    const float* __restrict__ raw_positions,
    const float* __restrict__ g_w0, const float* __restrict__ g_b0,
    const float* __restrict__ g_b1, const float* __restrict__ g_b2,
    const float* __restrict__ g_w3, const float* __restrict__ g_b3,
    const float* __restrict__ g_lmr,
    const f16*   __restrict__ wt,
    float* __restrict__ out)
{
    const int tid  = threadIdx.x;
    const int wave = tid >> 6;
    const int lane = tid & 63;
    const int u = lane & 15, g = lane >> 4;

    const int gw   = blockIdx.x * 4 + wave;  // global wave id = image-row id
    const int b    = gw >> 6;
    const int irow = gw & 63;

    const float cx = -1.0f + (2.0f/63.0f)*(float)lane;
    const float cy = -1.0f + (2.0f/63.0f)*(float)irow;

    const int pid = __builtin_amdgcn_readfirstlane(program_id[b]);
    const int ns  = (pid == 0) ? 1 : 2;

    float p0 = 0.f, p1 = 0.f;

    #pragma unroll 1
    for (int s = 0; s < ns; ++s) {
        const int pg = __builtin_amdgcn_readfirstlane(shape_ids[b*2 + s]);
        const float rx = raw_positions[(b*2+s)*2 + 0];
        const float ry = raw_positions[(b*2+s)*2 + 1];
        const float posx = 1.f/(1.f + expf(-rx)) - 0.5f;
        const float posy = 1.f/(1.f + expf(-ry)) - 0.5f;
        const float dx = cx - posx, dy = cy - posy;
        const float theta = atan2f(dy, dx);

        // thetas of the 4 pixel-columns this lane covers in B-fragments
        float th[4];
        #pragma unroll
        for (int nt = 0; nt < 4; ++nt) th[nt] = __shfl(theta, 16*nt + u);

        // ---- layer 0 (1->64): straight into MFMA B-fragment registers
        // bf[nt][kh][i] = relu(theta_pix * w0[k] + b0[k]), k = 32kh+8g+i
        f16x8 bf[4][2];
        {
            const float* w0p = g_w0 + pg*HID;
            const float* b0p = g_b0 + pg*HID;
            f32x4 w0r[2][2], b0r[2][2];
            #pragma unroll
            for (int kh = 0; kh < 2; ++kh)
                #pragma unroll
                for (int q = 0; q < 2; ++q) {
                    w0r[kh][q] = *(const f32x4*)(w0p + 32*kh + 8*g + 4*q);
                    b0r[kh][q] = *(const f32x4*)(b0p + 32*kh + 8*g + 4*q);
                }
            #pragma unroll
            for (int nt = 0; nt < 4; ++nt)
                #pragma unroll
                for (int kh = 0; kh < 2; ++kh) {
                    union { f16x2 h2[4]; f16x8 v8; } uu;
                    #pragma unroll
                    for (int q = 0; q < 2; ++q)
                        #pragma unroll
                        for (int j = 0; j < 4; j += 2) {
                            float a = fmaxf(fmaf(th[nt], w0r[kh][q][j],   b0r[kh][q][j]),   0.f);
                            float c = fmaxf(fmaf(th[nt], w0r[kh][q][j+1], b0r[kh][q][j+1]), 0.f);
                            uu.h2[q*2 + j/2] = cvt2(a, c);
                        }
                    bf[nt][kh] = uu.v8;
                }
        }

        // ---- layer 1: all 16 accumulators live; D[chan][pixel]
        // acc[mt][nt][j]: chan = 16mt+4g+j, pixel = 16nt+u
        f32x4 acc[4][4];
        #pragma unroll
        for (int mt = 0; mt < 4; ++mt) {
            const f16x8 wf0 = *(const f16x8*)&wt[(((pg*4+mt)*2+0)*64 + lane)*8];
            const f16x8 wf1 = *(const f16x8*)&wt[(((pg*4+mt)*2+1)*64 + lane)*8];
            const f32x4 bv  = *(const f32x4*)(g_b1 + pg*HID + 16*mt + 4*g);
            #pragma unroll
            for (int nt = 0; nt < 4; ++nt) {
                f32x4 a = bv;
                a = __builtin_amdgcn_mfma_f32_16x16x32_f16(wf0, bf[nt][0], a, 0,0,0);
                a = __builtin_amdgcn_mfma_f32_16x16x32_f16(wf1, bf[nt][1], a, 0,0,0);
                acc[mt][nt] = a;
            }
        }

        // ---- repack h1 into layer-2 B-fragments, purely in-lane:
        // cf[nt][kh][j] = relu(acc[2kh + (j>>2)][nt][j&3])  (k-perm baked into wt2)
        f16x8 cf[4][2];
        #pragma unroll
        for (int nt = 0; nt < 4; ++nt)
            #pragma unroll
            for (int kh = 0; kh < 2; ++kh) {
                union { f16x2 h2[4]; f16x8 v8; } uu;
                #pragma unroll
                for (int hhalf = 0; hhalf < 2; ++hhalf) {
                    const f32x4 av = acc[2*kh + hhalf][nt];
                    uu.h2[hhalf*2+0] = cvt2(fmaxf(av[0],0.f), fmaxf(av[1],0.f));
                    uu.h2[hhalf*2+1] = cvt2(fmaxf(av[2],0.f), fmaxf(av[3],0.f));
                }
                cf[nt][kh] = uu.v8;
            }

        // ---- layer 2 + head fused (weights from permuted-k wt2)
        {
            const f16* wt2 = wt + 8192;
            float hp[4] = {0.f, 0.f, 0.f, 0.f};
            #pragma unroll
            for (int mt = 0; mt < 4; ++mt) {
                const f16x8 wf0 = *(const f16x8*)&wt2[(((pg*4+mt)*2+0)*64 + lane)*8];
                const f16x8 wf1 = *(const f16x8*)&wt2[(((pg*4+mt)*2+1)*64 + lane)*8];
                const f32x4 bv  = *(const f32x4*)(g_b2 + pg*HID + 16*mt + 4*g);
                const f32x4 w3v = *(const f32x4*)(g_w3 + pg*HID + 16*mt + 4*g);
                #pragma unroll
                for (int nt = 0; nt < 4; ++nt) {
                    f32x4 a = bv;
                    a = __builtin_amdgcn_mfma_f32_16x16x32_f16(wf0, cf[nt][0], a, 0,0,0);
                    a = __builtin_amdgcn_mfma_f32_16x16x32_f16(wf1, cf[nt][1], a, 0,0,0);
                    hp[nt] += fmaxf(a[0],0.f)*w3v[0] + fmaxf(a[1],0.f)*w3v[1]
                            + fmaxf(a[2],0.f)*w3v[2] + fmaxf(a[3],0.f)*w3v[3];
                }
            }
            #pragma unroll
            for (int nt = 0; nt < 4; ++nt) {
                hp[nt] += __shfl_xor(hp[nt], 16);
                hp[nt] += __shfl_xor(hp[nt], 32);
            }
            float ov = hp[0];
            if (g == 1) ov = hp[1];
            if (g == 2) ov = hp[2];
            if (g == 3) ov = hp[3];
            ov += g_b3[pg];

            const float mult  = expf(g_lmr[pg]);
            const float r2    = sqrtf(dx*dx + dy*dy);
            const float logit = mult * (expf(ov) - r2);
            const float p     = 1.f/(1.f + expf(-logit));
            if (s == 0) p0 = p; else p1 = p;
        }
    }

    float res;
    if (pid == 0) {
        res = p0;
    } else {
        float c = (pid == 2) ? (p0 - p1) : (p0 + p1);
        res = fminf(fmaxf(c, 0.f), 1.f);
    }
    out[b*(IM*IM) + irow*64 + lane] = res;
}

extern "C" void kernel_launch(void* const* d_in, const int* in_sizes, int n_in,
                              void* d_out, int out_size, void* d_ws, size_t ws_size,
                              hipStream_t stream) {
    const int*   program_id    = (const int*)  d_in[0];
    const int*   shape_ids     = (const int*)  d_in[1];
    const float* raw_positions = (const float*)d_in[2];
    const float* w0            = (const float*)d_in[3];
    const float* b0            = (const float*)d_in[4];
    const float* w1            = (const float*)d_in[5];
    const float* b1            = (const float*)d_in[6];
    const float* w2            = (const float*)d_in[7];
    const float* b2            = (const float*)d_in[8];
    const float* w3            = (const float*)d_in[9];
    const float* b3            = (const float*)d_in[10];
    const float* lmr           = (const float*)d_in[11];
    float* out = (float*)d_out;
    f16*   wt  = (f16*)d_ws;                 // 2 x 8192 f16 = 32 KB

    prep_kernel<<<64, 256, 0, stream>>>(w1, w2, wt);

    genmodel_kernel<<<NBATCH*16, 256, 0, stream>>>(
        program_id, shape_ids, raw_positions,
        w0, b0, b1, b2, w3, b3, lmr, wt, out);
}

// Round 8
// 80.397 us; speedup vs baseline: 1.1949x; 1.0214x over previous
//
#include <hip/hip_runtime.h>
#include <math.h>

#define IM 64
#define NBATCH 256
#define HID 64

typedef _Float16 f16;
typedef _Float16 f16x8 __attribute__((ext_vector_type(8)));
typedef _Float16 f16x2 __attribute__((ext_vector_type(2)));
typedef float    f32x4 __attribute__((ext_vector_type(4)));
typedef float    f32x2 __attribute__((ext_vector_type(2)));

// ws layout (f16 units unless noted):
//   [0,8192)      wt1: A-frag W1, (((pg*4+mt)*2+kh)*64+lane)*8+j ; k=32kh+8g+j
//   [8192,16384)  wt2: A-frag W2, same addr ; k=32kh+16(j>>2)+4g+(j&3)  (perm
//                 matches layer-1 accumulator layout -> in-lane repack, no LDS)
//   float idx [8192,10240): sc[(b*2+s)*4] = {posx, posy, exp(lmr[pg]), b3[pg]}
__global__ void prep_kernel(const float* __restrict__ w1,
                            const float* __restrict__ w2,
                            const int*   __restrict__ shape_ids,
                            const float* __restrict__ raw_positions,
                            const float* __restrict__ lmr,
                            const float* __restrict__ b3,
                            f16* __restrict__ wt) {
    int idx = blockIdx.x * 256 + threadIdx.x;     // 0..18431
    if (idx < 16384) {
        int half = idx >> 13, r = idx & 8191;
        int j = r & 7, lane = (r >> 3) & 63, kh = (r >> 9) & 1;
        int mt = (r >> 10) & 3, pg = (r >> 12) & 1;
        int u = lane & 15, g = lane >> 4, n = 16*mt + u;
        int k; const float* w;
        if (half == 0) { k = 32*kh + 8*g + j;                 w = w1; }
        else           { k = 32*kh + 16*(j>>2) + 4*g + (j&3); w = w2; }
        wt[idx] = (f16)w[pg*4096 + k*64 + n];
    } else if (idx < 18432) {
        int r = idx - 16384;                      // 0..2047
        int e = r >> 2, c = r & 3;                // e = b*2+s
        float v;
        if (c == 0)      v = 1.f/(1.f + __expf(-raw_positions[e*2+0])) - 0.5f;
        else if (c == 1) v = 1.f/(1.f + __expf(-raw_positions[e*2+1])) - 0.5f;
        else if (c == 2) v = __expf(lmr[shape_ids[e]]);
        else             v = b3[shape_ids[e]];
        ((float*)wt)[8192 + r] = v;
    }
}

static __device__ __forceinline__ f16x2 cvt2(float a, float b) {
    return __builtin_bit_cast(f16x2, __builtin_amdgcn_cvt_pkrtz(a, b));
}
static __device__ __forceinline__ f32x2 pmax2(f32x2 v) {
    return __builtin_elementwise_max(v, (f32x2)0.f);
}
// minimax atan2, max err ~2e-7 rad; theta only feeds the f16 MLP input.
static __device__ __forceinline__ float fast_atan2(float y, float x) {
    float ax = fabsf(x), ay = fabsf(y);
    float mx = fmaxf(ax, ay), mn = fminf(ax, ay);
    float t = mn * __builtin_amdgcn_rcpf(mx);
    float z = t * t;
    float p = fmaf(z, -0.01172120f, 0.05265332f);
    p = fmaf(z, p, -0.11643287f);
    p = fmaf(z, p,  0.19354346f);
    p = fmaf(z, p, -0.33262347f);
    p = fmaf(z, p,  0.99997726f);
    float r = t * p;
    r = (ay > ax)  ? 1.5707964f - r : r;
    r = (x < 0.f)  ? 3.1415927f - r : r;
    return (y < 0.f) ? -r : r;
}

// 256-thread blocks = 4 independent waves (4 image rows of one image).
// NO LDS, NO barriers. f32 math in packed f32x2 (v_pk_fma_f32/v_pk_max_f32).
__global__ __launch_bounds__(256, 2) void genmodel_kernel(
    const int*   __restrict__ program_id,
    const int*   __restrict__ shape_ids,
    const float* __restrict__ g_w0, const float* __restrict__ g_b0,
    const float* __restrict__ g_b1, const float* __restrict__ g_b2,
    const float* __restrict__ g_w3,
    const f16*   __restrict__ wt,
    float* __restrict__ out)
{
    const int tid  = threadIdx.x;
    const int wave = tid >> 6;
    const int lane = tid & 63;
    const int u = lane & 15, g = lane >> 4;

    const int gw   = blockIdx.x * 4 + wave;  // global wave id = image-row id
    const int b    = gw >> 6;
    const int irow = gw & 63;

    const float cx = -1.0f + (2.0f/63.0f)*(float)lane;
    const float cy = -1.0f + (2.0f/63.0f)*(float)irow;

    const int pid = __builtin_amdgcn_readfirstlane(program_id[b]);
    const int ns  = (pid == 0) ? 1 : 2;
    const float* sc = (const float*)wt + 8192;

    float p0 = 0.f, p1 = 0.f;

    #pragma unroll 1
    for (int s = 0; s < ns; ++s) {
        const int pg = __builtin_amdgcn_readfirstlane(shape_ids[b*2 + s]);
        const f32x4 scv = *(const f32x4*)&sc[(b*2 + s)*4];
        const float dx = cx - scv[0], dy = cy - scv[1];
        const float theta = fast_atan2(dy, dx);

        float th[4];
        #pragma unroll
        for (int nt = 0; nt < 4; ++nt) th[nt] = __shfl(theta, 16*nt + u);

        // ---- layer 0 (1->64) straight into B-fragments, packed f32x2 math
        f16x8 bf[4][2];
        {
            const float* w0p = g_w0 + pg*HID;
            const float* b0p = g_b0 + pg*HID;
            f32x4 w0q[2][2], b0q[2][2];
            #pragma unroll
            for (int kh = 0; kh < 2; ++kh)
                #pragma unroll
                for (int q = 0; q < 2; ++q) {
                    w0q[kh][q] = *(const f32x4*)(w0p + 32*kh + 8*g + 4*q);
                    b0q[kh][q] = *(const f32x4*)(b0p + 32*kh + 8*g + 4*q);
                }
            #pragma unroll
            for (int nt = 0; nt < 4; ++nt) {
                const f32x2 th2 = {th[nt], th[nt]};
                #pragma unroll
                for (int kh = 0; kh < 2; ++kh) {
                    union { f16x2 h2[4]; f16x8 v8; } uu;
                    #pragma unroll
                    for (int q = 0; q < 2; ++q) {
                        f32x2 w01 = {w0q[kh][q][0], w0q[kh][q][1]};
                        f32x2 w23 = {w0q[kh][q][2], w0q[kh][q][3]};
                        f32x2 c01 = {b0q[kh][q][0], b0q[kh][q][1]};
                        f32x2 c23 = {b0q[kh][q][2], b0q[kh][q][3]};
                        f32x2 v01 = pmax2(th2*w01 + c01);
                        f32x2 v23 = pmax2(th2*w23 + c23);
                        uu.h2[q*2+0] = cvt2(v01[0], v01[1]);
                        uu.h2[q*2+1] = cvt2(v23[0], v23[1]);
                    }
                    bf[nt][kh] = uu.v8;
                }
            }
        }

        // ---- layer 1: acc[mt][nt][j]: chan=16mt+4g+j, pixel=16nt+u
        f32x4 acc[4][4];
        #pragma unroll
        for (int mt = 0; mt < 4; ++mt) {
            const f16x8 wf0 = *(const f16x8*)&wt[(((pg*4+mt)*2+0)*64 + lane)*8];
            const f16x8 wf1 = *(const f16x8*)&wt[(((pg*4+mt)*2+1)*64 + lane)*8];
            const f32x4 bv  = *(const f32x4*)(g_b1 + pg*HID + 16*mt + 4*g);
            #pragma unroll
            for (int nt = 0; nt < 4; ++nt) {
                f32x4 a = __builtin_amdgcn_mfma_f32_16x16x32_f16(wf0, bf[nt][0], bv, 0,0,0);
                a = __builtin_amdgcn_mfma_f32_16x16x32_f16(wf1, bf[nt][1], a, 0,0,0);
                acc[mt][nt] = a;
            }
        }

        // ---- in-lane repack h1 -> layer-2 B-fragments (perm baked into wt2)
        f16x8 cf[4][2];
        #pragma unroll
        for (int nt = 0; nt < 4; ++nt)
            #pragma unroll
            for (int kh = 0; kh < 2; ++kh) {
                union { f16x2 h2[4]; f16x8 v8; } uu;
                #pragma unroll
                for (int hh = 0; hh < 2; ++hh) {
                    const f32x4 av = acc[2*kh + hh][nt];
                    f32x2 m01 = pmax2((f32x2){av[0], av[1]});
                    f32x2 m23 = pmax2((f32x2){av[2], av[3]});
                    uu.h2[hh*2+0] = cvt2(m01[0], m01[1]);
                    uu.h2[hh*2+1] = cvt2(m23[0], m23[1]);
                }
                cf[nt][kh] = uu.v8;
            }

        // ---- layer 2 + head fused, packed f32x2 accumulation
        {
            const f16* wt2 = wt + 8192;
            f32x2 hp2[4] = {{0.f,0.f},{0.f,0.f},{0.f,0.f},{0.f,0.f}};
            #pragma unroll
            for (int mt = 0; mt < 4; ++mt) {
                const f16x8 wf0 = *(const f16x8*)&wt2[(((pg*4+mt)*2+0)*64 + lane)*8];
                const f16x8 wf1 = *(const f16x8*)&wt2[(((pg*4+mt)*2+1)*64 + lane)*8];
                const f32x4 bv  = *(const f32x4*)(g_b2 + pg*HID + 16*mt + 4*g);
                const f32x4 w3v = *(const f32x4*)(g_w3 + pg*HID + 16*mt + 4*g);
                const f32x2 w301 = {w3v[0], w3v[1]}, w323 = {w3v[2], w3v[3]};
                #pragma unroll
                for (int nt = 0; nt < 4; ++nt) {
                    f32x4 a = __builtin_amdgcn_mfma_f32_16x16x32_f16(wf0, cf[nt][0], bv, 0,0,0);
                    a = __builtin_amdgcn_mfma_f32_16x16x32_f16(wf1, cf[nt][1], a, 0,0,0);
                    f32x2 e01 = pmax2((f32x2){a[0], a[1]});
                    f32x2 e23 = pmax2((f32x2){a[2], a[3]});
                    hp2[nt] = e01*w301 + hp2[nt];
                    hp2[nt] = e23*w323 + hp2[nt];
                }
            }
            float hp[4];
            #pragma unroll
            for (int nt = 0; nt < 4; ++nt) {
                hp[nt] = hp2[nt][0] + hp2[nt][1];
                hp[nt] += __shfl_xor(hp[nt], 16);
                hp[nt] += __shfl_xor(hp[nt], 32);
            }
            float ov = hp[0];
            if (g == 1) ov = hp[1];
            if (g == 2) ov = hp[2];
            if (g == 3) ov = hp[3];
            ov += scv[3];

            const float r2    = sqrtf(dx*dx + dy*dy);
            const float logit = scv[2] * (__expf(ov) - r2);
            const float p     = __builtin_amdgcn_rcpf(1.f + __expf(-logit));
            if (s == 0) p0 = p; else p1 = p;
        }
    }

    float res;
    if (pid == 0) {
        res = p0;
    } else {
        float c = (pid == 2) ? (p0 - p1) : (p0 + p1);
        res = fminf(fmaxf(c, 0.f), 1.f);
    }
    out[b*(IM*IM) + irow*64 + lane] = res;
}

extern "C" void kernel_launch(void* const* d_in, const int* in_sizes, int n_in,
                              void* d_out, int out_size, void* d_ws, size_t ws_size,
                              hipStream_t stream) {
    const int*   program_id    = (const int*)  d_in[0];
    const int*   shape_ids     = (const int*)  d_in[1];
    const float* raw_positions = (const float*)d_in[2];
    const float* w0            = (const float*)d_in[3];
    const float* b0            = (const float*)d_in[4];
    const float* w1            = (const float*)d_in[5];
    const float* b1            = (const float*)d_in[6];
    const float* w2            = (const float*)d_in[7];
    const float* b2            = (const float*)d_in[8];
    const float* w3            = (const float*)d_in[9];
    const float* b3            = (const float*)d_in[10];
    const float* lmr           = (const float*)d_in[11];
    float* out = (float*)d_out;
    f16*   wt  = (f16*)d_ws;                 // 32 KB frags + 8 KB scalar table

    prep_kernel<<<72, 256, 0, stream>>>(w1, w2, shape_ids, raw_positions,
                                        lmr, b3, wt);

    genmodel_kernel<<<NBATCH*16, 256, 0, stream>>>(
        program_id, shape_ids, w0, b0, b1, b2, w3, wt, out);
}

// Round 9
// 72.910 us; speedup vs baseline: 1.3176x; 1.1027x over previous
//
#include <hip/hip_runtime.h>
#include <math.h>

#define IM 64
#define NBATCH 256
#define HID 64
#define NWAVES 4096              // 1024 blocks x 4 waves; 16384 row-items / 4096 = 4 items/wave

typedef _Float16 f16;
typedef _Float16 f16x8 __attribute__((ext_vector_type(8)));
typedef _Float16 f16x2 __attribute__((ext_vector_type(2)));
typedef float    f32x4 __attribute__((ext_vector_type(4)));
typedef float    f32x2 __attribute__((ext_vector_type(2)));

// ws layout:
//  f16 [0,16384)      : MFMA A-frags. wt1 (idx<8192): k=32kh+8g+j (std);
//                       wt2: k=32kh+16(j>>2)+4g+(j&3) (perm = L1-acc layout)
//  f16 [16384,16640)  : w0h/b0h: pg*128 + c (w0), pg*128+64+c (b0)
//  f32 [8320,10368)   : scv[(b*2+s)*4] = {posx, posy, exp(lmr[pg]), b3[pg]}
//  f32 [10368,10752)  : b1 (128) | b2 (128) | w3 (128), pg-major (pg*64+c)
__global__ void prep_kernel(const float* __restrict__ w1,
                            const float* __restrict__ w2,
                            const float* __restrict__ w0,
                            const float* __restrict__ b0,
                            const float* __restrict__ b1,
                            const float* __restrict__ b2,
                            const float* __restrict__ w3,
                            const int*   __restrict__ shape_ids,
                            const float* __restrict__ raw_positions,
                            const float* __restrict__ lmr,
                            const float* __restrict__ b3,
                            f16* __restrict__ ws) {
    float* wsf = (float*)ws;
    int idx = blockIdx.x * 256 + threadIdx.x;
    if (idx < 16384) {
        int half = idx >> 13, r = idx & 8191;
        int j = r & 7, lane = (r >> 3) & 63, kh = (r >> 9) & 1;
        int mt = (r >> 10) & 3, pg = (r >> 12) & 1;
        int u = lane & 15, g = lane >> 4, n = 16*mt + u;
        int k; const float* w;
        if (half == 0) { k = 32*kh + 8*g + j;                 w = w1; }
        else           { k = 32*kh + 16*(j>>2) + 4*g + (j&3); w = w2; }
        ws[idx] = (f16)w[pg*4096 + k*64 + n];
    } else if (idx < 16640) {
        int r = idx - 16384, pg = r >> 7, q = r & 127;
        int c = q & 63;
        float v = (q < 64) ? w0[pg*64 + c] : b0[pg*64 + c];
        ws[idx] = (f16)v;
    } else if (idx < 18688) {
        int r = idx - 16640;                  // 0..2047, e = b*2+s
        int e = r >> 2, c = r & 3;
        float v;
        if (c == 0)      v = 1.f/(1.f + __expf(-raw_positions[e*2+0])) - 0.5f;
        else if (c == 1) v = 1.f/(1.f + __expf(-raw_positions[e*2+1])) - 0.5f;
        else if (c == 2) v = __expf(lmr[shape_ids[e]]);
        else             v = b3[shape_ids[e]];
        wsf[8320 + r] = v;
    } else if (idx < 19072) {
        int r = idx - 18688;                  // 0..383
        int seg = r >> 7, q = r & 127, pg = q >> 6, c = q & 63;
        const float* src = (seg == 0) ? b1 : (seg == 1) ? b2 : w3;
        wsf[10368 + r] = src[pg*64 + c];
    }
}

static __device__ __forceinline__ f16x2 cvt2(float a, float b) {
    return __builtin_bit_cast(f16x2, __builtin_amdgcn_cvt_pkrtz(a, b));
}
static __device__ __forceinline__ f32x2 pmax2(f32x2 v) {
    return __builtin_elementwise_max(v, (f32x2)0.f);
}
static __device__ __forceinline__ f16x2 hmax2(f16x2 v) {
    return __builtin_elementwise_max(v, (f16x2)(_Float16)0.f);
}
// minimax atan2, max err ~2e-7 rad
static __device__ __forceinline__ float fast_atan2(float y, float x) {
    float ax = fabsf(x), ay = fabsf(y);
    float mx = fmaxf(ax, ay), mn = fminf(ax, ay);
    float t = mn * __builtin_amdgcn_rcpf(mx);
    float z = t * t;
    float p = fmaf(z, -0.01172120f, 0.05265332f);
    p = fmaf(z, p, -0.11643287f);
    p = fmaf(z, p,  0.19354346f);
    p = fmaf(z, p, -0.33262347f);
    p = fmaf(z, p,  0.99997726f);
    float r = t * p;
    r = (ay > ax)  ? 1.5707964f - r : r;
    r = (x < 0.f)  ? 3.1415927f - r : r;
    return (y < 0.f) ? -r : r;
}

// Persistent-ish: 1024 blocks x 4 waves; each wave handles 4 (image,row)
// items. All weights/biases staged in LDS once per block (one barrier).
// Waves are independent afterwards. f16 packed math for L0 (v_pk_fma_f16
// is truly 2x; pk_f32 is NOT - R8 lesson).
__global__ __launch_bounds__(256, 2) void genmodel_kernel(
    const int* __restrict__ program_id,
    const int* __restrict__ shape_ids,
    const f16* __restrict__ ws,
    float* __restrict__ out)
{
    __shared__ f32x4 ldsbuf[2176];           // 34816 B
    f16*   ldsh = (f16*)ldsbuf;
    float* ldsb = (float*)((char*)ldsbuf + 33280);
    const float* wsf = (const float*)ws;

    const int tid  = threadIdx.x;
    const int wave = tid >> 6;
    const int lane = tid & 63;
    const int u = lane & 15, g = lane >> 4;

    // ---- stage weights: f16 bytes [0,33280) + bias bytes [41472,43008)
    {
        const f32x4* ws4 = (const f32x4*)ws;
        #pragma unroll
        for (int r = 0; r < 9; ++r) {
            int idx = r*256 + tid;
            if (idx < 2176) {
                int src = (idx < 2080) ? idx : 2592 + (idx - 2080);
                ldsbuf[idx] = ws4[src];
            }
        }
    }
    __syncthreads();                          // the only barrier

    const int gw = blockIdx.x * 4 + wave;     // wave id in [0,4096)

    #pragma unroll 1
    for (int it = 0; it < 4; ++it) {
        const int gi   = gw + it*NWAVES;      // row-item
        const int b    = gi >> 6;
        const int irow = gi & 63;

        const float cx = -1.0f + (2.0f/63.0f)*(float)lane;
        const float cy = -1.0f + (2.0f/63.0f)*(float)irow;

        const int pid = __builtin_amdgcn_readfirstlane(program_id[b]);
        const int ns  = (pid == 0) ? 1 : 2;

        float p0 = 0.f, p1 = 0.f;

        #pragma unroll 1
        for (int s = 0; s < ns; ++s) {
            const int pg = __builtin_amdgcn_readfirstlane(shape_ids[b*2 + s]);
            const f32x4 scv = *(const f32x4*)&wsf[8320 + (b*2 + s)*4];
            const float dx = cx - scv[0], dy = cy - scv[1];
            const float theta = fast_atan2(dy, dx);

            float th[4];
            #pragma unroll
            for (int nt = 0; nt < 4; ++nt) th[nt] = __shfl(theta, 16*nt + u);

            // ---- layer 0 (1->64): packed f16 straight into B-fragments
            f16x8 bf[4][2];
            {
                const f16* w0h = &ldsh[16384 + pg*128];
                f16x8 w0r[2], b0r[2];
                #pragma unroll
                for (int kh = 0; kh < 2; ++kh) {
                    w0r[kh] = *(const f16x8*)&w0h[32*kh + 8*g];
                    b0r[kh] = *(const f16x8*)&w0h[64 + 32*kh + 8*g];
                }
                #pragma unroll
                for (int nt = 0; nt < 4; ++nt) {
                    const f16 thh = (f16)th[nt];
                    const f16x2 th2 = {thh, thh};
                    #pragma unroll
                    for (int kh = 0; kh < 2; ++kh) {
                        union { f16x2 h2[4]; f16x8 v8; } uu;
                        union { f16x8 v8; f16x2 h2[4]; } wv, bv_;
                        wv.v8 = w0r[kh]; bv_.v8 = b0r[kh];
                        #pragma unroll
                        for (int q = 0; q < 4; ++q)
                            uu.h2[q] = hmax2(__builtin_elementwise_fma(th2, wv.h2[q], bv_.h2[q]));
                        bf[nt][kh] = uu.v8;
                    }
                }
            }

            // ---- layer 1: acc[mt][nt][j]: chan=16mt+4g+j, pixel=16nt+u
            f32x4 acc[4][4];
            #pragma unroll
            for (int mt = 0; mt < 4; ++mt) {
                const f16x8 wf0 = *(const f16x8*)&ldsh[(((pg*4+mt)*2+0)*64 + lane)*8];
                const f16x8 wf1 = *(const f16x8*)&ldsh[(((pg*4+mt)*2+1)*64 + lane)*8];
                const f32x4 bv  = *(const f32x4*)&ldsb[pg*64 + 16*mt + 4*g];
                #pragma unroll
                for (int nt = 0; nt < 4; ++nt) {
                    f32x4 a = __builtin_amdgcn_mfma_f32_16x16x32_f16(wf0, bf[nt][0], bv, 0,0,0);
                    a = __builtin_amdgcn_mfma_f32_16x16x32_f16(wf1, bf[nt][1], a, 0,0,0);
                    acc[mt][nt] = a;
                }
            }

            // ---- in-lane repack h1 -> L2 B-fragments (perm baked into wt2)
            f16x8 cf[4][2];
            #pragma unroll
            for (int nt = 0; nt < 4; ++nt)
                #pragma unroll
                for (int kh = 0; kh < 2; ++kh) {
                    union { f16x2 h2[4]; f16x8 v8; } uu;
                    #pragma unroll
                    for (int hh = 0; hh < 2; ++hh) {
                        const f32x4 av = acc[2*kh + hh][nt];
                        uu.h2[hh*2+0] = hmax2(cvt2(av[0], av[1]));
                        uu.h2[hh*2+1] = hmax2(cvt2(av[2], av[3]));
                    }
                    cf[nt][kh] = uu.v8;
                }

            // ---- layer 2 + head fused
            {
                f32x2 hp2[4] = {{0.f,0.f},{0.f,0.f},{0.f,0.f},{0.f,0.f}};
                #pragma unroll
                for (int mt = 0; mt < 4; ++mt) {
                    const f16x8 wf0 = *(const f16x8*)&ldsh[8192 + (((pg*4+mt)*2+0)*64 + lane)*8];
                    const f16x8 wf1 = *(const f16x8*)&ldsh[8192 + (((pg*4+mt)*2+1)*64 + lane)*8];
                    const f32x4 bv  = *(const f32x4*)&ldsb[128 + pg*64 + 16*mt + 4*g];
                    const f32x4 w3v = *(const f32x4*)&ldsb[256 + pg*64 + 16*mt + 4*g];
                    const f32x2 w301 = {w3v[0], w3v[1]}, w323 = {w3v[2], w3v[3]};
                    #pragma unroll
                    for (int nt = 0; nt < 4; ++nt) {
                        f32x4 a = __builtin_amdgcn_mfma_f32_16x16x32_f16(wf0, cf[nt][0], bv, 0,0,0);
                        a = __builtin_amdgcn_mfma_f32_16x16x32_f16(wf1, cf[nt][1], a, 0,0,0);
                        f32x2 e01 = pmax2((f32x2){a[0], a[1]});
                        f32x2 e23 = pmax2((f32x2){a[2], a[3]});
                        hp2[nt] = e01*w301 + hp2[nt];
                        hp2[nt] = e23*w323 + hp2[nt];
                    }
                }
                float hp[4];
                #pragma unroll
                for (int nt = 0; nt < 4; ++nt) {
                    hp[nt] = hp2[nt][0] + hp2[nt][1];
                    hp[nt] += __shfl_xor(hp[nt], 16);
                    hp[nt] += __shfl_xor(hp[nt], 32);
                }
                float ov = hp[0];
                if (g == 1) ov = hp[1];
                if (g == 2) ov = hp[2];
                if (g == 3) ov = hp[3];
                ov += scv[3];

                const float r2    = sqrtf(dx*dx + dy*dy);
                const float logit = scv[2] * (__expf(ov) - r2);
                const float p     = __builtin_amdgcn_rcpf(1.f + __expf(-logit));
                if (s == 0) p0 = p; else p1 = p;
            }
        }

        float res;
        if (pid == 0) {
            res = p0;
        } else {
            float c = (pid == 2) ? (p0 - p1) : (p0 + p1);
            res = fminf(fmaxf(c, 0.f), 1.f);
        }
        out[b*(IM*IM) + irow*64 + lane] = res;
    }
}

extern "C" void kernel_launch(void* const* d_in, const int* in_sizes, int n_in,
                              void* d_out, int out_size, void* d_ws, size_t ws_size,
                              hipStream_t stream) {
    const int*   program_id    = (const int*)  d_in[0];
    const int*   shape_ids     = (const int*)  d_in[1];
    const float* raw_positions = (const float*)d_in[2];
    const float* w0            = (const float*)d_in[3];
    const float* b0            = (const float*)d_in[4];
    const float* w1            = (const float*)d_in[5];
    const float* b1            = (const float*)d_in[6];
    const float* w2            = (const float*)d_in[7];
    const float* b2            = (const float*)d_in[8];
    const float* w3            = (const float*)d_in[9];
    const float* b3            = (const float*)d_in[10];
    const float* lmr           = (const float*)d_in[11];
    float* out = (float*)d_out;
    f16*   ws  = (f16*)d_ws;                  // 43 KB used

    prep_kernel<<<75, 256, 0, stream>>>(w1, w2, w0, b0, b1, b2, w3,
                                        shape_ids, raw_positions, lmr, b3, ws);

    genmodel_kernel<<<1024, 256, 0, stream>>>(program_id, shape_ids, ws, out);
}